// Round 3
// baseline (25.363 us; speedup 1.0000x reference)
//
#include <hip/hip_runtime.h>
#include <hip/hip_bf16.h>

// out[b,s,d] = x[b,s,d] + pe[s,d]
// pe[s,d] = sin((s+1) * 10000^(-d/D))        if d even
//         = cos((s+1) * 10000^(-(d+1)/D))    if d odd
// Shapes fixed by the reference: B=4, S=4096, D=1024, fp32 in/out.
//
// Streaming mapping with 2-deep MLP: each block covers 2048 contiguous
// floats (= exactly 2 rows of D=1024); each thread owns two float4s one
// row apart (same d, s differs by 1) -> one exp2 per j serves both.
// Nontemporal load/store: zero-reuse stream, skip cache allocation.

#define PE_S 4096
#define PE_D 1024
#define PE_B 4

typedef float f32x4 __attribute__((ext_vector_type(4)));

__global__ __launch_bounds__(256) void pe_add_kernel(const float* __restrict__ x,
                                                     float* __restrict__ out) {
    // quad index of this thread's first float4; block covers 512 quads
    const int q0 = blockIdx.x * 512 + threadIdx.x;
    const int q1 = q0 + 256;                                 // one D-row later

    const int dq = q0 & (PE_D / 4 - 1);                      // same for q0,q1
    const int d0 = dq * 4;
    const int s0 = (q0 >> 8) & (PE_S - 1);
    const int s1 = (q1 >> 8) & (PE_S - 1);                   // handles batch wrap

    const float pos0 = (float)(s0 + 1);
    const float pos1 = (float)(s1 + 1);
    const float c = -13.287712379549449f / (float)PE_D;      // -log2(10000)/D

    float pe0[4], pe1[4];
#pragma unroll
    for (int j = 0; j < 4; ++j) {
        const int d = d0 + j;
        const int exp_idx = (d & 1) ? (d + 1) : d;
        const float inv_freq = exp2f((float)exp_idx * c);    // shared by both rows
        const float a0 = pos0 * inv_freq;
        const float a1 = pos1 * inv_freq;
        if (d & 1) { pe0[j] = __cosf(a0); pe1[j] = __cosf(a1); }
        else       { pe0[j] = __sinf(a0); pe1[j] = __sinf(a1); }
    }

    const f32x4* __restrict__ xp0 = reinterpret_cast<const f32x4*>(x) + q0;
    const f32x4* __restrict__ xp1 = reinterpret_cast<const f32x4*>(x) + q1;
    f32x4* __restrict__ op0 = reinterpret_cast<f32x4*>(out) + q0;
    f32x4* __restrict__ op1 = reinterpret_cast<f32x4*>(out) + q1;

    // issue both loads before either use (2 vmem in flight per thread)
    f32x4 xv0 = __builtin_nontemporal_load(xp0);
    f32x4 xv1 = __builtin_nontemporal_load(xp1);

    f32x4 ov0, ov1;
    ov0.x = xv0.x + pe0[0]; ov0.y = xv0.y + pe0[1];
    ov0.z = xv0.z + pe0[2]; ov0.w = xv0.w + pe0[3];
    ov1.x = xv1.x + pe1[0]; ov1.y = xv1.y + pe1[1];
    ov1.z = xv1.z + pe1[2]; ov1.w = xv1.w + pe1[3];

    __builtin_nontemporal_store(ov0, op0);
    __builtin_nontemporal_store(ov1, op1);
}

extern "C" void kernel_launch(void* const* d_in, const int* in_sizes, int n_in,
                              void* d_out, int out_size, void* d_ws, size_t ws_size,
                              hipStream_t stream) {
    const float* x = (const float*)d_in[0];
    float* out = (float*)d_out;

    const int threads = 256;
    const int total_quads = PE_B * PE_S * (PE_D / 4);        // 4,194,304 quads
    const int blocks = total_quads / (threads * 2);          // 8192 blocks
    pe_add_kernel<<<blocks, threads, 0, stream>>>(x, out);
}

// Round 4
// 24.656 us; speedup vs baseline: 1.0287x; 1.0287x over previous
//
#include <hip/hip_runtime.h>
#include <hip/hip_bf16.h>

// out[b,s,d] = x[b,s,d] + pe[s,d]
// pe[s,d] = sin((s+1) * 10000^(-d/D))        if d even
//         = cos((s+1) * 10000^(-(d+1)/D))    if d odd
// Shapes fixed by the reference: B=4, S=4096, D=1024, fp32 in/out.
//
// Round-2 mapping (best so far: 24.2 us): 1 thread = 1 float4, 1 load +
// 1 store, sequential addresses. ONLY change vs round 2: nontemporal
// load/store (zero-reuse stream -> skip cache allocation). Isolates the
// nt variable after round 3's bundled regression.

#define PE_S 4096
#define PE_D 1024
#define PE_B 4

typedef float f32x4 __attribute__((ext_vector_type(4)));

__global__ __launch_bounds__(256) void pe_add_kernel(const float* __restrict__ x,
                                                     float* __restrict__ out) {
    const int idx = blockIdx.x * blockDim.x + threadIdx.x;   // over B*S*D/4
    const int dq = idx & (PE_D / 4 - 1);                     // which float4 along D
    const int s  = (idx >> 8) & (PE_S - 1);                  // D/4 = 256 quads/row
    const int d0 = dq * 4;

    const float pos = (float)(s + 1);
    // inv_freq = 10000^(-exp_idx/D) = exp2(-exp_idx * log2(10000)/D)
    const float c = -13.287712379549449f / (float)PE_D;      // -log2(10000)/D

    float pe[4];
#pragma unroll
    for (int j = 0; j < 4; ++j) {
        const int d = d0 + j;
        const int exp_idx = (d & 1) ? (d + 1) : d;
        const float inv_freq = exp2f((float)exp_idx * c);
        const float angle = pos * inv_freq;
        pe[j] = (d & 1) ? __cosf(angle) : __sinf(angle);
    }

    const f32x4* __restrict__ xp = reinterpret_cast<const f32x4*>(x) + idx;
    f32x4* __restrict__ op = reinterpret_cast<f32x4*>(out) + idx;

    const f32x4 xv = __builtin_nontemporal_load(xp);
    f32x4 ov;
    ov.x = xv.x + pe[0];
    ov.y = xv.y + pe[1];
    ov.z = xv.z + pe[2];
    ov.w = xv.w + pe[3];
    __builtin_nontemporal_store(ov, op);
}

extern "C" void kernel_launch(void* const* d_in, const int* in_sizes, int n_in,
                              void* d_out, int out_size, void* d_ws, size_t ws_size,
                              hipStream_t stream) {
    const float* x = (const float*)d_in[0];
    float* out = (float*)d_out;

    const int threads = 256;
    const int total_quads = PE_B * PE_S * (PE_D / 4);        // 4,194,304 quads
    const int blocks = total_quads / threads;                // 16384 blocks
    pe_add_kernel<<<blocks, threads, 0, stream>>>(x, out);
}

// Round 5
// 24.278 us; speedup vs baseline: 1.0447x; 1.0155x over previous
//
#include <hip/hip_runtime.h>
#include <hip/hip_bf16.h>

// out[b,s,d] = x[b,s,d] + pe[s,d]
// pe[s,d] = sin((s+1) * 10000^(-d/D))        if d even
//         = cos((s+1) * 10000^(-(d+1)/D))    if d odd
// Shapes fixed by the reference: B=4, S=4096, D=1024, fp32 in/out.
//
// FINAL (round-2 variant, best measured: 24.20 us = ~94% of the 6.29 TB/s
// read+write copy ceiling after launch overhead). 1 thread = 1 float4,
// 1 load + 1 store, sequential addresses. Falsified by single-variable
// A/B: 2-deep MLP (25.4 us), nontemporal load/store (24.7 us).
// PE recomputed per thread: ~1.6 us of full-chip VALU, hidden under HBM.

#define PE_S 4096
#define PE_D 1024
#define PE_B 4

__global__ __launch_bounds__(256) void pe_add_kernel(const float* __restrict__ x,
                                                     float* __restrict__ out) {
    const int idx = blockIdx.x * blockDim.x + threadIdx.x;   // over B*S*D/4
    const int dq = idx & (PE_D / 4 - 1);                     // which float4 along D
    const int s  = (idx >> 8) & (PE_S - 1);                  // D/4 = 256 quads/row
    const int d0 = dq * 4;

    const float pos = (float)(s + 1);
    // inv_freq = 10000^(-exp_idx/D) = exp2(-exp_idx * log2(10000)/D)
    const float c = -13.287712379549449f / (float)PE_D;      // -log2(10000)/D

    float pe[4];
#pragma unroll
    for (int j = 0; j < 4; ++j) {
        const int d = d0 + j;
        const int exp_idx = (d & 1) ? (d + 1) : d;
        const float inv_freq = exp2f((float)exp_idx * c);
        const float angle = pos * inv_freq;
        pe[j] = (d & 1) ? __cosf(angle) : __sinf(angle);
    }

    const size_t off = (size_t)idx * 4;
    const float4 xv = *reinterpret_cast<const float4*>(x + off);
    float4 ov;
    ov.x = xv.x + pe[0];
    ov.y = xv.y + pe[1];
    ov.z = xv.z + pe[2];
    ov.w = xv.w + pe[3];
    *reinterpret_cast<float4*>(out + off) = ov;
}

extern "C" void kernel_launch(void* const* d_in, const int* in_sizes, int n_in,
                              void* d_out, int out_size, void* d_ws, size_t ws_size,
                              hipStream_t stream) {
    const float* x = (const float*)d_in[0];
    float* out = (float*)d_out;

    const int threads = 256;
    const int total_quads = PE_B * PE_S * (PE_D / 4);        // 4,194,304 quads
    const int blocks = total_quads / threads;                // 16384 blocks
    pe_add_kernel<<<blocks, threads, 0, stream>>>(x, out);
}